// Round 1
// baseline (172.139 us; speedup 1.0000x reference)
//
#include <hip/hip_runtime.h>
#include <stdint.h>

typedef unsigned short u16;
typedef __attribute__((ext_vector_type(8))) short short8;   // bf16x8 MFMA frag (4 VGPR)
typedef __attribute__((ext_vector_type(4))) float f32x4;    // MFMA C/D frag

#define LOG2E 1.44269504088896340736f

// ---------- helpers ----------
static __device__ __forceinline__ unsigned pack_bf16(float lo, float hi){
    unsigned r;
    asm("v_cvt_pk_bf16_f32 %0, %1, %2" : "=v"(r) : "v"(lo), "v"(hi));
    return r;
}
static __device__ __forceinline__ u16 f2bf(float f){
    return (u16)(pack_bf16(f, f) & 0xffffu);
}
static __device__ __forceinline__ void glds16(const void* gsrc, void* ldst){
    __builtin_amdgcn_global_load_lds((const __attribute__((address_space(1))) void*)gsrc,
                                     (__attribute__((address_space(3))) void*)ldst, 16, 0, 0);
}
static __device__ __forceinline__ short8 lds_read8(const u16* p){
    return *(const short8*)(const void*)p;
}

// ---------- f32 -> bf16 converts ----------
__global__ __launch_bounds__(256) void cvt2(const float* __restrict__ s0, u16* __restrict__ d0,
                                            const float* __restrict__ s1, u16* __restrict__ d1){
    const float* s = blockIdx.y ? s1 : s0;
    u16* d = blockIdx.y ? d1 : d0;
    size_t i = ((size_t)blockIdx.x*256 + threadIdx.x)*4;
    float4 v = *(const float4*)(s + i);
    uint2 o; o.x = pack_bf16(v.x, v.y); o.y = pack_bf16(v.z, v.w);
    *(uint2*)(d + i) = o;
}
__global__ __launch_bounds__(256) void cvt4(const float* __restrict__ s0, u16* __restrict__ d0,
                                            const float* __restrict__ s1, u16* __restrict__ d1,
                                            const float* __restrict__ s2, u16* __restrict__ d2,
                                            const float* __restrict__ s3, u16* __restrict__ d3){
    const float* s; u16* d;
    switch (blockIdx.y){
        case 0: s=s0; d=d0; break;
        case 1: s=s1; d=d1; break;
        case 2: s=s2; d=d2; break;
        default: s=s3; d=d3; break;
    }
    size_t i = ((size_t)blockIdx.x*256 + threadIdx.x)*4;
    float4 v = *(const float4*)(s + i);
    uint2 o; o.x = pack_bf16(v.x, v.y); o.y = pack_bf16(v.z, v.w);
    *(uint2*)(d + i) = o;
}

// ---------- bias transpose: biasT[k][q] = bias[q][k] ----------
__global__ __launch_bounds__(256) void transpose_bias(const float* __restrict__ bias,
                                                      float* __restrict__ biasT){
    __shared__ float t[32][33];
    int x = threadIdx.x & 31, y8 = threadIdx.x >> 5;
    int bx = blockIdx.x, by = blockIdx.y;
    #pragma unroll
    for (int r = 0; r < 4; ++r){
        int row = y8*4 + r;
        t[row][x] = bias[(size_t)(by*32 + row)*2048 + bx*32 + x];
    }
    __syncthreads();
    #pragma unroll
    for (int r = 0; r < 4; ++r){
        int row = y8*4 + r;
        biasT[(size_t)(bx*32 + row)*2048 + by*32 + x] = t[x][row];
    }
}

// ---------- GEMM core: C[128x64] = A[128xK] @ W[64xK]^T (bf16 in, f32 acc) ----------
// LDS tiles swizzled: granule slot s holds data granule s ^ ((row>>1)&3); 2-way banks = free.
static __device__ __forceinline__ void gemm_core(const u16* __restrict__ A, const u16* __restrict__ W,
                                                 u16* As, u16* Bs, int mblk, int nblk,
                                                 f32x4 acc[4][2]){
    const int tid = threadIdx.x, lane = tid & 63, w = tid >> 6;
    const int g = lane >> 4, q15 = lane & 15;
    const int wm = w >> 1, wn = w & 1;
    const int srow = lane >> 2, sc = lane & 3;
    for (int kt = 0; kt < 32; ++kt){
        #pragma unroll
        for (int ii = 0; ii < 2; ++ii){
            int i = w*2 + ii;
            int row = i*16 + srow;
            int c = sc ^ ((row >> 1) & 3);
            glds16(A + (size_t)(mblk*128 + row)*1024 + kt*32 + c*8, As + i*512);
        }
        {
            int row = w*16 + srow;
            int c = sc ^ ((row >> 1) & 3);
            glds16(W + (size_t)(nblk*64 + row)*1024 + kt*32 + c*8, Bs + w*512);
        }
        __syncthreads();
        short8 af[4], bfr[2];
        #pragma unroll
        for (int mf = 0; mf < 4; ++mf){
            int row = wm*64 + mf*16 + q15;
            af[mf] = lds_read8(As + row*32 + ((g ^ ((row >> 1) & 3)) * 8));
        }
        #pragma unroll
        for (int nf = 0; nf < 2; ++nf){
            int row = wn*32 + nf*16 + q15;
            bfr[nf] = lds_read8(Bs + row*32 + ((g ^ ((row >> 1) & 3)) * 8));
        }
        #pragma unroll
        for (int mf = 0; mf < 4; ++mf)
            #pragma unroll
            for (int nf = 0; nf < 2; ++nf)
                acc[mf][nf] = __builtin_amdgcn_mfma_f32_16x16x32_bf16(af[mf], bfr[nf], acc[mf][nf], 0, 0, 0);
        __syncthreads();
    }
}

// ---------- QKV projection (z=0:Q scaled, z=1:K, z=2:V transposed) ----------
__global__ __launch_bounds__(256, 4)
void gemm_qkv(const u16* __restrict__ xb, const u16* __restrict__ yb,
              const u16* __restrict__ wq, const u16* __restrict__ wk, const u16* __restrict__ wv,
              u16* __restrict__ Qb, u16* __restrict__ Kb, u16* __restrict__ Vt){
    __shared__ u16 As[128*32];
    __shared__ u16 Bs[64*32];
    const int z = blockIdx.z;
    const u16* A = (z == 0) ? xb : yb;
    const u16* W = (z == 0) ? wq : ((z == 1) ? wk : wv);
    const int mblk = blockIdx.y, nblk = blockIdx.x;
    f32x4 acc[4][2] = {};
    gemm_core(A, W, As, Bs, mblk, nblk, acc);

    const int tid = threadIdx.x, lane = tid & 63, w = tid >> 6;
    const int g = lane >> 4, q15 = lane & 15;
    const int wm = w >> 1, wn = w & 1;
    if (z == 2){
        // Vt[((b*16+h)*64 + d)*2048 + l]
        #pragma unroll
        for (int mf = 0; mf < 4; ++mf){
            int m0 = mblk*128 + wm*64 + mf*16 + g*4;
            int b = m0 >> 11, l0 = m0 & 2047;
            #pragma unroll
            for (int nf = 0; nf < 2; ++nf){
                int n = nblk*64 + wn*32 + nf*16 + q15;
                int h = n >> 6, d = n & 63;
                uint2 pk;
                pk.x = pack_bf16(acc[mf][nf][0], acc[mf][nf][1]);
                pk.y = pack_bf16(acc[mf][nf][2], acc[mf][nf][3]);
                *(uint2*)(Vt + (size_t)((b*16 + h)*64 + d)*2048 + l0) = pk;
            }
        }
    } else {
        const float scale = (z == 0) ? 0.125f : 1.0f;   // DEPTH^-0.5 folded into Q
        u16* O = (z == 0) ? Qb : Kb;
        #pragma unroll
        for (int mf = 0; mf < 4; ++mf)
            #pragma unroll
            for (int nf = 0; nf < 2; ++nf){
                int n = nblk*64 + wn*32 + nf*16 + q15;
                #pragma unroll
                for (int r = 0; r < 4; ++r){
                    int m = mblk*128 + wm*64 + mf*16 + g*4 + r;
                    O[(size_t)m*1024 + n] = f2bf(acc[mf][nf][r]*scale);
                }
            }
    }
}

// ---------- output projection: d_out = attn @ wo^T (f32 out) ----------
__global__ __launch_bounds__(256, 4)
void gemm_out(const u16* __restrict__ A, const u16* __restrict__ W, float* __restrict__ O){
    __shared__ u16 As[128*32];
    __shared__ u16 Bs[64*32];
    const int mblk = blockIdx.y, nblk = blockIdx.x;
    f32x4 acc[4][2] = {};
    gemm_core(A, W, As, Bs, mblk, nblk, acc);
    const int tid = threadIdx.x, lane = tid & 63, w = tid >> 6;
    const int g = lane >> 4, q15 = lane & 15;
    const int wm = w >> 1, wn = w & 1;
    #pragma unroll
    for (int mf = 0; mf < 4; ++mf)
        #pragma unroll
        for (int nf = 0; nf < 2; ++nf){
            int n = nblk*64 + wn*32 + nf*16 + q15;
            #pragma unroll
            for (int r = 0; r < 4; ++r){
                int m = mblk*128 + wm*64 + mf*16 + g*4 + r;
                O[(size_t)m*1024 + n] = acc[mf][nf][r];
            }
        }
}

// ---------- fused attention ----------
// Grid (32 qblocks, 32 b*h). 4 waves x 16 q-rows. Computes S^T = mfma(K, Q) so the
// k-reduction of softmax is lane-local; PV computed as out^T = mfma(V^T, P^T).
__global__ __launch_bounds__(256, 4)
void attn_kernel(const u16* __restrict__ Qb, const u16* __restrict__ Kb,
                 const u16* __restrict__ Vt, const float* __restrict__ biasT,
                 u16* __restrict__ attn){
    __shared__ u16 Ks[64*64];   // [kpos][d], row = 128B, XOR-swizzled granules
    __shared__ u16 Vs[64*64];   // [d][kpos]
    const int qb = blockIdx.x, bh = blockIdx.y;
    const int b = bh >> 4, h = bh & 15;
    const int tid = threadIdx.x, lane = tid & 63, w = tid >> 6;
    const int g = lane >> 4, q15 = lane & 15;
    const int qrow = qb*64 + w*16 + q15;

    short8 qf[2];
    #pragma unroll
    for (int ks = 0; ks < 2; ++ks)
        qf[ks] = lds_read8(Qb + (size_t)(b*2048 + qrow)*1024 + h*64 + ks*32 + g*8);  // plain global load

    f32x4 acco[4] = {};
    float m_run = -3.0e38f, l_run = 0.0f;

    const int srow = lane >> 3, sc7 = lane & 7;
    const u16* Kbase = Kb + (size_t)b*2048*1024 + h*64;
    const u16* Vbase = Vt + (size_t)(b*16 + h)*64*2048;
    const float* btcol = biasT + qb*64 + w*16 + q15;

    for (int kt = 0; kt < 32; ++kt){
        #pragma unroll
        for (int ii = 0; ii < 2; ++ii){
            int i = w*2 + ii;
            int row = i*8 + srow;
            int c = sc7 ^ (row & 7);
            glds16(Kbase + (size_t)(kt*64 + row)*1024 + c*8, Ks + i*512);
            glds16(Vbase + (size_t)row*2048 + kt*64 + c*8, Vs + i*512);
        }
        __syncthreads();

        // S^T fragments + bias
        float s[16];
        #pragma unroll
        for (int mf = 0; mf < 4; ++mf){
            int row = mf*16 + q15;  // kpos
            short8 kf0 = lds_read8(Ks + row*64 + (((0 + g) ^ (row & 7)) * 8));
            short8 kf1 = lds_read8(Ks + row*64 + (((4 + g) ^ (row & 7)) * 8));
            f32x4 accs = {};
            accs = __builtin_amdgcn_mfma_f32_16x16x32_bf16(kf0, qf[0], accs, 0, 0, 0);
            accs = __builtin_amdgcn_mfma_f32_16x16x32_bf16(kf1, qf[1], accs, 0, 0, 0);
            #pragma unroll
            for (int r = 0; r < 4; ++r)
                s[mf*4 + r] = accs[r] + btcol[(size_t)(kt*64 + mf*16 + g*4 + r)*2048];
        }

        // online softmax (per q-row; lane-local 16 + 2 shfl_xor across the 4 lanes sharing q)
        float mt = s[0];
        #pragma unroll
        for (int i2 = 1; i2 < 16; ++i2) mt = fmaxf(mt, s[i2]);
        mt = fmaxf(mt, __shfl_xor(mt, 16));
        mt = fmaxf(mt, __shfl_xor(mt, 32));
        float mnew = fmaxf(m_run, mt);
        float corr = __builtin_amdgcn_exp2f((m_run - mnew)*LOG2E);
        float ts = 0.0f;
        #pragma unroll
        for (int i2 = 0; i2 < 16; ++i2){
            s[i2] = __builtin_amdgcn_exp2f((s[i2] - mnew)*LOG2E);
            ts += s[i2];
        }
        ts += __shfl_xor(ts, 16);
        ts += __shfl_xor(ts, 32);
        l_run = l_run*corr + ts;
        m_run = mnew;
        #pragma unroll
        for (int mf = 0; mf < 4; ++mf)
            #pragma unroll
            for (int r = 0; r < 4; ++r) acco[mf][r] *= corr;

        // pack P to bf16 pairs, shfl-redistribute into PV B-operand layout
        unsigned ph01[4], ph23[4];
        #pragma unroll
        for (int f = 0; f < 4; ++f){
            ph01[f] = pack_bf16(s[f*4 + 0], s[f*4 + 1]);
            ph23[f] = pack_bf16(s[f*4 + 2], s[f*4 + 3]);
        }
        const int src0 = ((g & 1)*2)*16 + q15;
        const int src1 = src0 + 16;
        const bool hi = (g >> 1) != 0;
        #pragma unroll
        for (int ks = 0; ks < 2; ++ks){
            unsigned aA = (unsigned)__shfl((int)ph01[ks*2],     src0);
            unsigned aB = (unsigned)__shfl((int)ph01[ks*2 + 1], src0);
            unsigned bA = (unsigned)__shfl((int)ph23[ks*2],     src0);
            unsigned bB = (unsigned)__shfl((int)ph23[ks*2 + 1], src0);
            unsigned cA = (unsigned)__shfl((int)ph01[ks*2],     src1);
            unsigned cB = (unsigned)__shfl((int)ph01[ks*2 + 1], src1);
            unsigned dA = (unsigned)__shfl((int)ph23[ks*2],     src1);
            unsigned dB = (unsigned)__shfl((int)ph23[ks*2 + 1], src1);
            union { unsigned u[4]; short8 v; } pb;
            pb.u[0] = hi ? aB : aA;
            pb.u[1] = hi ? bB : bA;
            pb.u[2] = hi ? cB : cA;
            pb.u[3] = hi ? dB : dA;
            #pragma unroll
            for (int mf = 0; mf < 4; ++mf){
                int drow = mf*16 + q15;  // d
                short8 vf = lds_read8(Vs + drow*64 + (((ks*4 + g) ^ (drow & 7)) * 8));
                acco[mf] = __builtin_amdgcn_mfma_f32_16x16x32_bf16(vf, pb.v, acco[mf], 0, 0, 0);
            }
        }
        __syncthreads();
    }

    const float inv = 1.0f / l_run;
    #pragma unroll
    for (int mf = 0; mf < 4; ++mf){
        uint2 pk;
        pk.x = pack_bf16(acco[mf][0]*inv, acco[mf][1]*inv);
        pk.y = pack_bf16(acco[mf][2]*inv, acco[mf][3]*inv);
        *(uint2*)(attn + (size_t)(b*2048 + qrow)*1024 + h*64 + mf*16 + g*4) = pk;
    }
}

// ---------- launch ----------
extern "C" void kernel_launch(void* const* d_in, const int* in_sizes, int n_in,
                              void* d_out, int out_size, void* d_ws, size_t ws_size,
                              hipStream_t stream){
    (void)in_sizes; (void)n_in; (void)out_size; (void)ws_size;
    const float* x    = (const float*)d_in[0];
    const float* y    = (const float*)d_in[1];
    const float* bias = (const float*)d_in[2];
    const float* wq   = (const float*)d_in[3];
    const float* wk   = (const float*)d_in[4];
    const float* wv   = (const float*)d_in[5];
    const float* wo   = (const float*)d_in[6];
    float* out = (float*)d_out;

    u16* xb    = (u16*)d_ws;
    u16* yb    = xb  + 4194304;
    u16* wqb   = yb  + 4194304;
    u16* wkb   = wqb + 1048576;
    u16* wvb   = wkb + 1048576;
    u16* wob   = wvb + 1048576;
    u16* Qb    = wob + 1048576;
    u16* Kb    = Qb  + 4194304;
    u16* Vt    = Kb  + 4194304;
    u16* attnb = Vt  + 4194304;
    float* biasT = (float*)(attnb + 4194304);   // 16 MB; total ws use ~75.5 MB

    cvt2<<<dim3(4096, 2), 256, 0, stream>>>(x, xb, y, yb);
    cvt4<<<dim3(1024, 4), 256, 0, stream>>>(wq, wqb, wk, wkb, wv, wvb, wo, wob);
    transpose_bias<<<dim3(64, 64), 256, 0, stream>>>(bias, biasT);
    gemm_qkv<<<dim3(16, 32, 3), 256, 0, stream>>>(xb, yb, wqb, wkb, wvb, Qb, Kb, Vt);
    attn_kernel<<<dim3(32, 32), 256, 0, stream>>>(Qb, Kb, Vt, biasT, attnb);
    gemm_out<<<dim3(16, 32), 256, 0, stream>>>(attnb, wob, out);
}

// Round 3
// 166.730 us; speedup vs baseline: 1.0324x; 1.0324x over previous
//
#include <hip/hip_runtime.h>
#include <stdint.h>

typedef unsigned short u16;
typedef __attribute__((ext_vector_type(8))) short short8;   // bf16x8 MFMA frag (4 VGPR)
typedef __attribute__((ext_vector_type(4))) float f32x4;    // MFMA C/D frag

#define LOG2E 1.44269504088896340736f
#define MFMA16(a,b,c) __builtin_amdgcn_mfma_f32_16x16x32_bf16((a),(b),(c),0,0,0)

// ---------- helpers ----------
static __device__ __forceinline__ unsigned pack_bf16(float lo, float hi){
    unsigned r;
    asm("v_cvt_pk_bf16_f32 %0, %1, %2" : "=v"(r) : "v"(lo), "v"(hi));
    return r;
}
static __device__ __forceinline__ u16 f2bf(float f){
    return (u16)(pack_bf16(f, f) & 0xffffu);
}
static __device__ __forceinline__ void glds16(const void* gsrc, void* ldst){
    __builtin_amdgcn_global_load_lds((const __attribute__((address_space(1))) void*)gsrc,
                                     (__attribute__((address_space(3))) void*)ldst, 16, 0, 0);
}
static __device__ __forceinline__ short8 lds_read8(const u16* p){
    return *(const short8*)(const void*)p;
}

// ---------- f32 -> bf16 converts ----------
__global__ __launch_bounds__(256) void cvt2(const float* __restrict__ s0, u16* __restrict__ d0,
                                            const float* __restrict__ s1, u16* __restrict__ d1){
    const float* s = blockIdx.y ? s1 : s0;
    u16* d = blockIdx.y ? d1 : d0;
    size_t i = ((size_t)blockIdx.x*256 + threadIdx.x)*4;
    float4 v = *(const float4*)(s + i);
    uint2 o; o.x = pack_bf16(v.x, v.y); o.y = pack_bf16(v.z, v.w);
    *(uint2*)(d + i) = o;
}
__global__ __launch_bounds__(256) void cvt4(const float* __restrict__ s0, u16* __restrict__ d0,
                                            const float* __restrict__ s1, u16* __restrict__ d1,
                                            const float* __restrict__ s2, u16* __restrict__ d2,
                                            const float* __restrict__ s3, u16* __restrict__ d3){
    const float* s; u16* d;
    switch (blockIdx.y){
        case 0: s=s0; d=d0; break;
        case 1: s=s1; d=d1; break;
        case 2: s=s2; d=d2; break;
        default: s=s3; d=d3; break;
    }
    size_t i = ((size_t)blockIdx.x*256 + threadIdx.x)*4;
    float4 v = *(const float4*)(s + i);
    uint2 o; o.x = pack_bf16(v.x, v.y); o.y = pack_bf16(v.z, v.w);
    *(uint2*)(d + i) = o;
}

// ---------- bias transpose: biasT[k][q] = bias[q][k] ----------
__global__ __launch_bounds__(256) void transpose_bias(const float* __restrict__ bias,
                                                      float* __restrict__ biasT){
    __shared__ float t[32][33];
    int x = threadIdx.x & 31, y8 = threadIdx.x >> 5;
    int bx = blockIdx.x, by = blockIdx.y;
    #pragma unroll
    for (int r = 0; r < 4; ++r){
        int row = y8*4 + r;
        t[row][x] = bias[(size_t)(by*32 + row)*2048 + bx*32 + x];
    }
    __syncthreads();
    #pragma unroll
    for (int r = 0; r < 4; ++r){
        int row = y8*4 + r;
        biasT[(size_t)(bx*32 + row)*2048 + by*32 + x] = t[x][row];
    }
}

// ---------- GEMM body: C[128 x NFR*32] = A[128xK] @ W[(NFR*32)xK]^T ----------
// 2-phase double-buffered pipeline; LDS granule-swizzled (slot = c ^ ((row>>1)&3)).
template<int NFR>
static __device__ __forceinline__ void gemm_body(const u16* __restrict__ A, const u16* __restrict__ W,
                                                 u16* As, u16* Bs, int mblk, int nblk,
                                                 f32x4 (&acc)[4][NFR]){
    const int tid = threadIdx.x, lane = tid & 63, w = tid >> 6;
    const int g = lane >> 4, q15 = lane & 15;
    const int wm = w >> 1, wn = w & 1;
    const int srow = lane >> 2, sc = lane & 3;

    auto stage = [&](int buf, int kt){
        u16* Ab = As + buf*4096;
        u16* Bb = Bs + buf*(NFR*1024);
        #pragma unroll
        for (int ii = 0; ii < 2; ++ii){
            int i = w*2 + ii;
            int row = i*16 + srow;
            int c = sc ^ ((row >> 1) & 3);
            glds16(A + (size_t)(mblk*128 + row)*1024 + kt*32 + c*8, Ab + i*512);
        }
        #pragma unroll
        for (int ii = 0; ii < NFR/2; ++ii){
            int i = w*(NFR/2) + ii;
            int row = i*16 + srow;
            int c = sc ^ ((row >> 1) & 3);
            glds16(W + (size_t)(nblk*(NFR*32) + row)*1024 + kt*32 + c*8, Bb + i*512);
        }
    };
    auto compute = [&](int buf){
        const u16* Ab = As + buf*4096;
        const u16* Bb = Bs + buf*(NFR*1024);
        short8 af[4], bfr[NFR];
        #pragma unroll
        for (int mf = 0; mf < 4; ++mf){
            int row = wm*64 + mf*16 + q15;
            af[mf] = lds_read8(Ab + row*32 + ((g ^ ((row >> 1) & 3)) * 8));
        }
        #pragma unroll
        for (int nf = 0; nf < NFR; ++nf){
            int row = wn*(NFR*16) + nf*16 + q15;
            bfr[nf] = lds_read8(Bb + row*32 + ((g ^ ((row >> 1) & 3)) * 8));
        }
        #pragma unroll
        for (int mf = 0; mf < 4; ++mf)
            #pragma unroll
            for (int nf = 0; nf < NFR; ++nf)
                acc[mf][nf] = MFMA16(af[mf], bfr[nf], acc[mf][nf]);
    };

    stage(0, 0);
    __syncthreads();
    #pragma unroll 1
    for (int kt = 0; kt < 30; kt += 2){
        stage(1, kt + 1);
        compute(0);
        __syncthreads();
        stage(0, kt + 2);
        compute(1);
        __syncthreads();
    }
    stage(1, 31);
    compute(0);
    __syncthreads();
    compute(1);
}

// ---------- QKV projection (z=0:Q scaled, z=1:K, z=2:V transposed), 128x128 tiles ----------
__global__ __launch_bounds__(256, 3)
void gemm_qkv(const u16* __restrict__ xb, const u16* __restrict__ yb,
              const u16* __restrict__ wq, const u16* __restrict__ wk, const u16* __restrict__ wv,
              u16* __restrict__ Qb, u16* __restrict__ Kb, u16* __restrict__ Vt){
    __shared__ u16 As[2*4096];
    __shared__ u16 Bs[2*4096];
    const int z = blockIdx.z;
    const u16* A = (z == 0) ? xb : yb;
    const u16* W = (z == 0) ? wq : ((z == 1) ? wk : wv);
    const int mblk = blockIdx.y, nblk = blockIdx.x;
    f32x4 acc[4][4] = {};
    gemm_body<4>(A, W, As, Bs, mblk, nblk, acc);

    const int tid = threadIdx.x, lane = tid & 63, w = tid >> 6;
    const int g = lane >> 4, q15 = lane & 15;
    const int wm = w >> 1, wn = w & 1;
    if (z == 2){
        // Vt[((b*16+h)*64 + d)*2048 + l]
        #pragma unroll
        for (int mf = 0; mf < 4; ++mf){
            int m0 = mblk*128 + wm*64 + mf*16 + g*4;
            int b = m0 >> 11, l0 = m0 & 2047;
            #pragma unroll
            for (int nf = 0; nf < 4; ++nf){
                int n = nblk*128 + wn*64 + nf*16 + q15;
                int h = n >> 6, d = n & 63;
                uint2 pk;
                pk.x = pack_bf16(acc[mf][nf][0], acc[mf][nf][1]);
                pk.y = pack_bf16(acc[mf][nf][2], acc[mf][nf][3]);
                *(uint2*)(Vt + (size_t)((b*16 + h)*64 + d)*2048 + l0) = pk;
            }
        }
    } else {
        const float scale = (z == 0) ? 0.125f : 1.0f;   // DEPTH^-0.5 folded into Q
        u16* O = (z == 0) ? Qb : Kb;
        #pragma unroll
        for (int mf = 0; mf < 4; ++mf)
            #pragma unroll
            for (int nf = 0; nf < 4; ++nf){
                int n = nblk*128 + wn*64 + nf*16 + q15;
                #pragma unroll
                for (int r = 0; r < 4; ++r){
                    int m = mblk*128 + wm*64 + mf*16 + g*4 + r;
                    O[(size_t)m*1024 + n] = f2bf(acc[mf][nf][r]*scale);
                }
            }
    }
}

// ---------- output projection: d_out = attn @ wo^T (f32 out), 128x64 tiles ----------
__global__ __launch_bounds__(256, 4)
void gemm_out(const u16* __restrict__ A, const u16* __restrict__ W, float* __restrict__ O){
    __shared__ u16 As[2*4096];
    __shared__ u16 Bs[2*2048];
    const int mblk = blockIdx.y, nblk = blockIdx.x;
    f32x4 acc[4][2] = {};
    gemm_body<2>(A, W, As, Bs, mblk, nblk, acc);
    const int tid = threadIdx.x, lane = tid & 63, w = tid >> 6;
    const int g = lane >> 4, q15 = lane & 15;
    const int wm = w >> 1, wn = w & 1;
    #pragma unroll
    for (int mf = 0; mf < 4; ++mf)
        #pragma unroll
        for (int nf = 0; nf < 2; ++nf){
            int n = nblk*64 + wn*32 + nf*16 + q15;
            #pragma unroll
            for (int r = 0; r < 4; ++r){
                int m = mblk*128 + wm*64 + mf*16 + g*4 + r;
                O[(size_t)m*1024 + n] = acc[mf][nf][r];
            }
        }
}

// ---------- fused attention (R1-verbatim: single-buffer, always-rescale) ----------
// Grid (32 qblocks, 32 b*h). 4 waves x 16 q-rows. Computes S^T = mfma(K, Q) so the
// k-reduction of softmax is lane-local; PV computed as out^T = mfma(V^T, P^T).
__global__ __launch_bounds__(256, 4)
void attn_kernel(const u16* __restrict__ Qb, const u16* __restrict__ Kb,
                 const u16* __restrict__ Vt, const float* __restrict__ biasT,
                 u16* __restrict__ attn){
    __shared__ u16 Ks[64*64];   // [kpos][d], row = 128B, XOR-swizzled granules
    __shared__ u16 Vs[64*64];   // [d][kpos]
    const int qb = blockIdx.x, bh = blockIdx.y;
    const int b = bh >> 4, h = bh & 15;
    const int tid = threadIdx.x, lane = tid & 63, w = tid >> 6;
    const int g = lane >> 4, q15 = lane & 15;
    const int qrow = qb*64 + w*16 + q15;

    short8 qf[2];
    #pragma unroll
    for (int ks = 0; ks < 2; ++ks)
        qf[ks] = lds_read8(Qb + (size_t)(b*2048 + qrow)*1024 + h*64 + ks*32 + g*8);  // plain global load

    f32x4 acco[4] = {};
    float m_run = -3.0e38f, l_run = 0.0f;

    const int srow = lane >> 3, sc7 = lane & 7;
    const u16* Kbase = Kb + (size_t)b*2048*1024 + h*64;
    const u16* Vbase = Vt + (size_t)(b*16 + h)*64*2048;
    const float* btcol = biasT + qb*64 + w*16 + q15;

    for (int kt = 0; kt < 32; ++kt){
        #pragma unroll
        for (int ii = 0; ii < 2; ++ii){
            int i = w*2 + ii;
            int row = i*8 + srow;
            int c = sc7 ^ (row & 7);
            glds16(Kbase + (size_t)(kt*64 + row)*1024 + c*8, Ks + i*512);
            glds16(Vbase + (size_t)row*2048 + kt*64 + c*8, Vs + i*512);
        }
        __syncthreads();

        // S^T fragments + bias
        float s[16];
        #pragma unroll
        for (int mf = 0; mf < 4; ++mf){
            int row = mf*16 + q15;  // kpos
            short8 kf0 = lds_read8(Ks + row*64 + (((0 + g) ^ (row & 7)) * 8));
            short8 kf1 = lds_read8(Ks + row*64 + (((4 + g) ^ (row & 7)) * 8));
            f32x4 accs = {};
            accs = MFMA16(kf0, qf[0], accs);
            accs = MFMA16(kf1, qf[1], accs);
            #pragma unroll
            for (int r = 0; r < 4; ++r)
                s[mf*4 + r] = accs[r] + btcol[(size_t)(kt*64 + mf*16 + g*4 + r)*2048];
        }

        // online softmax (per q-row; lane-local 16 + 2 shfl_xor across the 4 lanes sharing q)
        float mt = s[0];
        #pragma unroll
        for (int i2 = 1; i2 < 16; ++i2) mt = fmaxf(mt, s[i2]);
        mt = fmaxf(mt, __shfl_xor(mt, 16));
        mt = fmaxf(mt, __shfl_xor(mt, 32));
        float mnew = fmaxf(m_run, mt);
        float corr = __builtin_amdgcn_exp2f((m_run - mnew)*LOG2E);
        float ts = 0.0f;
        #pragma unroll
        for (int i2 = 0; i2 < 16; ++i2){
            s[i2] = __builtin_amdgcn_exp2f((s[i2] - mnew)*LOG2E);
            ts += s[i2];
        }
        ts += __shfl_xor(ts, 16);
        ts += __shfl_xor(ts, 32);
        l_run = l_run*corr + ts;
        m_run = mnew;
        #pragma unroll
        for (int mf = 0; mf < 4; ++mf)
            #pragma unroll
            for (int r = 0; r < 4; ++r) acco[mf][r] *= corr;

        // pack P to bf16 pairs, shfl-redistribute into PV B-operand layout
        unsigned ph01[4], ph23[4];
        #pragma unroll
        for (int f = 0; f < 4; ++f){
            ph01[f] = pack_bf16(s[f*4 + 0], s[f*4 + 1]);
            ph23[f] = pack_bf16(s[f*4 + 2], s[f*4 + 3]);
        }
        const int src0 = ((g & 1)*2)*16 + q15;
        const int src1 = src0 + 16;
        const bool hi = (g >> 1) != 0;
        #pragma unroll
        for (int ks = 0; ks < 2; ++ks){
            unsigned aA = (unsigned)__shfl((int)ph01[ks*2],     src0);
            unsigned aB = (unsigned)__shfl((int)ph01[ks*2 + 1], src0);
            unsigned bA = (unsigned)__shfl((int)ph23[ks*2],     src0);
            unsigned bB = (unsigned)__shfl((int)ph23[ks*2 + 1], src0);
            unsigned cA = (unsigned)__shfl((int)ph01[ks*2],     src1);
            unsigned cB = (unsigned)__shfl((int)ph01[ks*2 + 1], src1);
            unsigned dA = (unsigned)__shfl((int)ph23[ks*2],     src1);
            unsigned dB = (unsigned)__shfl((int)ph23[ks*2 + 1], src1);
            union { unsigned u[4]; short8 v; } pb;
            pb.u[0] = hi ? aB : aA;
            pb.u[1] = hi ? bB : bA;
            pb.u[2] = hi ? cB : cA;
            pb.u[3] = hi ? dB : dA;
            #pragma unroll
            for (int mf = 0; mf < 4; ++mf){
                int drow = mf*16 + q15;  // d
                short8 vf = lds_read8(Vs + drow*64 + (((ks*4 + g) ^ (drow & 7)) * 8));
                acco[mf] = MFMA16(vf, pb.v, acco[mf]);
            }
        }
        __syncthreads();
    }

    const float inv = 1.0f / l_run;
    #pragma unroll
    for (int mf = 0; mf < 4; ++mf){
        uint2 pk;
        pk.x = pack_bf16(acco[mf][0]*inv, acco[mf][1]*inv);
        pk.y = pack_bf16(acco[mf][2]*inv, acco[mf][3]*inv);
        *(uint2*)(attn + (size_t)(b*2048 + qrow)*1024 + h*64 + mf*16 + g*4) = pk;
    }
}

// ---------- launch ----------
extern "C" void kernel_launch(void* const* d_in, const int* in_sizes, int n_in,
                              void* d_out, int out_size, void* d_ws, size_t ws_size,
                              hipStream_t stream){
    (void)in_sizes; (void)n_in; (void)out_size; (void)ws_size;
    const float* x    = (const float*)d_in[0];
    const float* y    = (const float*)d_in[1];
    const float* bias = (const float*)d_in[2];
    const float* wq   = (const float*)d_in[3];
    const float* wk   = (const float*)d_in[4];
    const float* wv   = (const float*)d_in[5];
    const float* wo   = (const float*)d_in[6];
    float* out = (float*)d_out;

    u16* xb    = (u16*)d_ws;
    u16* yb    = xb  + 4194304;
    u16* wqb   = yb  + 4194304;
    u16* wkb   = wqb + 1048576;
    u16* wvb   = wkb + 1048576;
    u16* wob   = wvb + 1048576;
    u16* Qb    = wob + 1048576;
    u16* Kb    = Qb  + 4194304;
    u16* Vt    = Kb  + 4194304;
    u16* attnb = Vt  + 4194304;
    float* biasT = (float*)(attnb + 4194304);   // 16 MB; total ws use ~75.5 MB

    cvt2<<<dim3(4096, 2), 256, 0, stream>>>(x, xb, y, yb);
    cvt4<<<dim3(1024, 4), 256, 0, stream>>>(wq, wqb, wk, wkb, wv, wvb, wo, wob);
    transpose_bias<<<dim3(64, 64), 256, 0, stream>>>(bias, biasT);
    gemm_qkv<<<dim3(8, 32, 3), 256, 0, stream>>>(xb, yb, wqb, wkb, wvb, Qb, Kb, Vt);
    attn_kernel<<<dim3(32, 32), 256, 0, stream>>>(Qb, Kb, Vt, biasT, attnb);
    gemm_out<<<dim3(16, 32), 256, 0, stream>>>(attnb, wob, out);
}